// Round 14
// baseline (250.183 us; speedup 1.0000x reference)
//
#include <hip/hip_runtime.h>

#define NFEAT 128
#define BSHIFT 8
#define BNODES 256            // dst nodes per bucket
#define NBMAX 512             // max buckets (N <= 131072)
#define BCAP 5120             // fixed packed capacity per bucket (mean 4096 + ~16 sigma)
#define CHUNK 2048            // edges per partition block

typedef __attribute__((ext_vector_type(8))) short bf16x8;
typedef __attribute__((ext_vector_type(4))) float f32x4;
typedef unsigned short u16;

__device__ inline u16 f2bf(float f) {            // RNE
    unsigned u = __float_as_uint(f);
    u += 0x7FFF + ((u >> 16) & 1);
    return (u16)(u >> 16);
}
__device__ inline float bf2f(u16 h) {
    return __uint_as_float((unsigned)h << 16);
}

// ---------------- partition v4: LDS counting sort per chunk + coalesced flush ----------------
// 256 thr, CHUNK=2048 -> 782 blocks (~3/CU). packed[b*BCAP + slot] = ((dst&255)<<17)|src.
__global__ __launch_bounds__(256)
void partition_kernel(const int* __restrict__ src, const int* __restrict__ dst, int E,
                      int* __restrict__ cursor, int* __restrict__ packed,
                      int* __restrict__ out_deg, int NB) {
    __shared__ int cnt[NBMAX];            // hist -> local placement cursor
    __shared__ int loff[NBMAX];           // local exclusive offsets
    __shared__ int gbase[NBMAX];          // global run base per bucket
    __shared__ int sa[256], sb[256];
    __shared__ int sortv[CHUNK];          // 8 KiB sorted packed values
    __shared__ u16 sortb[CHUNK];          // 4 KiB bucket id per slot

    int tid = threadIdx.x;
    cnt[tid] = 0;
    cnt[tid + 256] = 0;
    __syncthreads();

    int base = blockIdx.x * CHUNK;
    int endj = min(base + CHUNK, E);
    int ccnt = endj - base;

    for (int j = base + tid; j < endj; j += 256) {
        atomicAdd(&out_deg[src[j]], 1);            // fused deg histogram (fire-and-forget)
        atomicAdd(&cnt[dst[j] >> BSHIFT], 1);
    }
    __syncthreads();

    // pair-scan over 512 bins with 256 threads
    int i0 = 2 * tid, i1 = 2 * tid + 1;
    int v0 = cnt[i0], v1 = cnt[i1];
    int pr = v0 + v1;
    sa[tid] = pr;
    __syncthreads();
    int* s = sa; int* t = sb;
    for (int d = 1; d < 256; d <<= 1) {
        t[tid] = s[tid] + (tid >= d ? s[tid - d] : 0);
        __syncthreads();
        int* tmp = s; s = t; t = tmp;
    }
    int excl = s[tid] - pr;
    loff[i0] = excl;      loff[i1] = excl + v0;
    cnt[i0]  = excl;      cnt[i1]  = excl + v0;       // placement cursors
    gbase[i0] = v0 ? (i0 * BCAP + atomicAdd(&cursor[i0], v0)) : 0;
    gbase[i1] = v1 ? (i1 * BCAP + atomicAdd(&cursor[i1], v1)) : 0;
    __syncthreads();

    for (int j = base + tid; j < endj; j += 256) {
        int d_ = dst[j];
        int bkt = d_ >> BSHIFT;
        int pos = atomicAdd(&cnt[bkt], 1);
        sortv[pos] = ((d_ & (BNODES - 1)) << 17) | src[j];
        sortb[pos] = (u16)bkt;
    }
    __syncthreads();

    // coalesced flush: consecutive p (same bucket run) -> consecutive global addresses
    for (int p = tid; p < ccnt; p += 256) {
        int bkt = sortb[p];
        packed[gbase[bkt] + (p - loff[bkt])] = sortv[p];
    }
}

// ---------------- fat kernel: binfill (blocks 0..NB-1) || cast (NB..NB+nbc-1) || Wt (last) ---
__global__ __launch_bounds__(512)
void fill_cast_kernel(const int* __restrict__ packed, const int* __restrict__ cursor,
                      int* __restrict__ row_start, float* __restrict__ inorm,
                      int* __restrict__ csr_src,
                      const float* __restrict__ x, const int* __restrict__ out_deg,
                      u16* __restrict__ xh, const float* __restrict__ W,
                      u16* __restrict__ Wt, int N, int E, int NB, int nbc) {
    int bid = blockIdx.x;
    int tid = threadIdx.x;

    if (bid < NB) {
        // ---- binfill: per-bucket node-sort of packed -> compact csr_src + row_start + inorm
        __shared__ int cnt[BNODES];
        __shared__ int sa[256], sb[256];
        __shared__ int excl2[NBMAX];
        int bkt = bid;
        int node0 = bkt << BSHIFT;
        int nn = min(BNODES, N - node0);
        int beg = bkt * BCAP;
        int ccnt = cursor[bkt];

        // in-block csr_base: pair-scan of cursor[0..NB) (<=512 bins, 256 scan threads)
        int i0 = 2 * tid, i1 = 2 * tid + 1;
        int v0 = 0, v1 = 0;
        if (tid < 256) {
            v0 = (i0 < NB) ? cursor[i0] : 0;
            v1 = (i1 < NB) ? cursor[i1] : 0;
            sa[tid] = v0 + v1;
        }
        __syncthreads();
        int* p = sa; int* q = sb;
        for (int d = 1; d < 256; d <<= 1) {
            if (tid < 256) q[tid] = p[tid] + (tid >= d ? p[tid - d] : 0);
            __syncthreads();
            int* tmp = p; p = q; q = tmp;
        }
        if (tid < 256) {
            int e2 = p[tid] - (v0 + v1);
            excl2[i0] = e2;
            excl2[i1] = e2 + v0;
        }
        __syncthreads();
        int csr0 = excl2[bkt];
        if (bkt == 0 && tid == 0) row_start[N] = E;

        if (tid < BNODES) cnt[tid] = 0;
        __syncthreads();
        for (int i = tid; i < ccnt; i += 512)
            atomicAdd(&cnt[packed[beg + i] >> 17], 1);
        __syncthreads();

        int v = (tid < BNODES) ? cnt[tid] : 0;
        if (tid < 256) sa[tid] = v;
        __syncthreads();
        int* s = sa; int* t = sb;
        for (int d = 1; d < 256; d <<= 1) {
            if (tid < 256) t[tid] = s[tid] + (tid >= d ? s[tid - d] : 0);
            __syncthreads();
            int* tmp = s; s = t; t = tmp;
        }
        int excl = (tid < BNODES) ? (s[tid] - v) : 0;

        if (tid < nn) {
            row_start[node0 + tid] = csr0 + excl;
            inorm[node0 + tid] = rsqrtf((float)max(v, 1));
        }
        __syncthreads();

        if (tid < BNODES) cnt[tid] = csr0 + excl;    // reuse as global cursor
        __syncthreads();
        for (int i = tid; i < ccnt; i += 512) {
            int pk = packed[beg + i];
            int slot = atomicAdd(&cnt[pk >> 17], 1);
            csr_src[slot] = pk & 0x1FFFF;
        }
    } else if (bid < NB + nbc) {
        // ---- cast: xh[n][:] = bf16(x[n][:] * rsqrt(max(out_deg[n],1))), 128 rows/block
        int node0 = (bid - NB) << 7;
        for (int i = tid; i < 128 * 32; i += 512) {
            int r = i >> 5, f4 = i & 31;
            int n = node0 + r;
            if (n >= N) break;
            float sc = rsqrtf((float)max(out_deg[n], 1));
            float4 vv = *reinterpret_cast<const float4*>(&x[(size_t)n * NFEAT + f4 * 4]);
            ushort4 o;
            o.x = f2bf(vv.x * sc); o.y = f2bf(vv.y * sc);
            o.z = f2bf(vv.z * sc); o.w = f2bf(vv.w * sc);
            *reinterpret_cast<ushort4*>(&xh[(size_t)n * NFEAT + f4 * 4]) = o;
        }
    } else {
        // ---- Wt[col][k] = bf16(W[k][col])
        for (int i = tid; i < NFEAT * NFEAT; i += 512) {
            int col = i >> 7, k = i & 127;
            Wt[i] = f2bf(W[k * NFEAT + col]);
        }
    }
}

// ---------------- gather-aggregate (round-6 proven): half-wave per node, 8-wide ILP ----------
// Writes agg row (bf16, inorm-scaled) STRIDED at d_out + node*512B (payload first 256B).
__global__ __launch_bounds__(256)
void agg_bf16_kernel(const u16* __restrict__ xh, const int* __restrict__ csr_src,
                     const int* __restrict__ row_start, const float* __restrict__ inorm,
                     u16* __restrict__ aggh, int N) {
    int node = blockIdx.x * 8 + (threadIdx.x >> 5);
    if (node >= N) return;
    int lf = threadIdx.x & 31;
    int beg = row_start[node];
    int end = row_start[node + 1];
    const ushort4* xr = reinterpret_cast<const ushort4*>(xh);

    float4 acc = make_float4(0.f, 0.f, 0.f, 0.f);
    for (int i = beg; i < end; i += 8) {
        int s[8];
        float m[8];
        #pragma unroll
        for (int u = 0; u < 8; ++u) {          // phase 1: 8 independent index loads
            int j = i + u;
            bool ok = (j < end);
            s[u] = ok ? csr_src[j] : 0;
            m[u] = ok ? 1.f : 0.f;
        }
        ushort4 v[8];
        #pragma unroll
        for (int u = 0; u < 8; ++u)            // phase 2: 8 independent row gathers
            v[u] = xr[(size_t)s[u] * 32 + lf];
        #pragma unroll
        for (int u = 0; u < 8; ++u) {          // phase 3: masked accumulate
            acc.x = fmaf(m[u], bf2f(v[u].x), acc.x);
            acc.y = fmaf(m[u], bf2f(v[u].y), acc.y);
            acc.z = fmaf(m[u], bf2f(v[u].z), acc.z);
            acc.w = fmaf(m[u], bf2f(v[u].w), acc.w);
        }
    }
    float in_n = inorm[node];
    ushort4 o;
    o.x = f2bf(acc.x * in_n);
    o.y = f2bf(acc.y * in_n);
    o.z = f2bf(acc.z * in_n);
    o.w = f2bf(acc.w * in_n);
    *reinterpret_cast<ushort4*>(aggh + (size_t)node * 256 + lf * 4) = o;
}

// ---------------- MFMA projection: out = aggh @ W + b, in-place; Wt read direct (L1-hot) ----
__global__ __launch_bounds__(256)
void mm_mfma_kernel(const u16* __restrict__ aggh, float* outp,
                    const u16* __restrict__ Wt, const float* __restrict__ b, int N) {
    __shared__ u16 Al[NFEAT * NFEAT];   // 32 KiB (only A staged; Wt via L1/L2)
    int tid = threadIdx.x;
    int r0 = blockIdx.x * 128;

    for (int c = tid; c < 2048; c += 256) {
        int row = c >> 4, sub = c & 15;
        int grow = min(r0 + row, N - 1);
        int slot = sub ^ (row & 7);
        *reinterpret_cast<uint4*>(reinterpret_cast<char*>(Al) + row * 256 + slot * 16) =
            *reinterpret_cast<const uint4*>(reinterpret_cast<const char*>(aggh) +
                                            (size_t)grow * 512 + sub * 16);
    }
    __syncthreads();

    int lane = tid & 63;
    int wave = tid >> 6;
    int wr = wave >> 1, wc = wave & 1;
    int lrow = lane & 15, hi = lane >> 4;

    f32x4 zero = {0.f, 0.f, 0.f, 0.f};
    f32x4 acc[4][4];
    #pragma unroll
    for (int rt = 0; rt < 4; ++rt)
        #pragma unroll
        for (int ct = 0; ct < 4; ++ct) acc[rt][ct] = zero;

    #pragma unroll
    for (int ks = 0; ks < 4; ++ks) {
        int chunk = ks * 4 + hi;
        bf16x8 af[4], bfr[4];
        #pragma unroll
        for (int rt = 0; rt < 4; ++rt) {
            int row = wr * 64 + rt * 16 + lrow;
            af[rt] = *reinterpret_cast<bf16x8*>(reinterpret_cast<char*>(Al) + row * 256 +
                                                ((chunk ^ (row & 7)) * 16));
        }
        #pragma unroll
        for (int ct = 0; ct < 4; ++ct) {
            int col = wc * 64 + ct * 16 + lrow;
            bfr[ct] = *reinterpret_cast<const bf16x8*>(Wt + col * NFEAT + chunk * 8);
        }
        #pragma unroll
        for (int rt = 0; rt < 4; ++rt)
            #pragma unroll
            for (int ct = 0; ct < 4; ++ct)
                acc[rt][ct] = __builtin_amdgcn_mfma_f32_16x16x32_bf16(af[rt], bfr[ct],
                                                                     acc[rt][ct], 0, 0, 0);
    }

    #pragma unroll
    for (int ct = 0; ct < 4; ++ct) {
        int col = wc * 64 + ct * 16 + lrow;
        float bias = b[col];
        #pragma unroll
        for (int rt = 0; rt < 4; ++rt) {
            int rbase = r0 + wr * 64 + rt * 16 + hi * 4;
            #pragma unroll
            for (int q = 0; q < 4; ++q) {
                int row = rbase + q;
                if (row < N) outp[(size_t)row * NFEAT + col] = acc[rt][ct][q] + bias;
            }
        }
    }
}

extern "C" void kernel_launch(void* const* d_in, const int* in_sizes, int n_in,
                              void* d_out, int out_size, void* d_ws, size_t ws_size,
                              hipStream_t stream) {
    const float* x   = (const float*)d_in[0];
    const int*   src = (const int*)d_in[1];
    const int*   dst = (const int*)d_in[2];
    const float* W   = (const float*)d_in[3];
    const float* b   = (const float*)d_in[4];

    const int N = in_sizes[0] / NFEAT;   // 100000
    const int E = in_sizes[1];           // 1600000
    float* out = (float*)d_out;

    const int NB = (N + BNODES - 1) >> BSHIFT;   // 391

    // ws layout (ints unless noted):
    // [out_deg N][cursor NBMAX]  <- zeroed together
    // [row_start N+1][inorm N f32][csr_src E][align][Wt 16384 bf16][xh N*128 bf16]
    int*   out_deg   = (int*)d_ws;
    int*   cursor    = out_deg + N;
    int*   row_start = cursor + NBMAX;
    float* inorm     = (float*)(row_start + (N + 1));
    int*   csr_src   = (int*)(inorm + N);
    uintptr_t wt_addr = ((uintptr_t)(csr_src + E) + 31) & ~(uintptr_t)31;
    u16*   Wt        = (u16*)wt_addr;
    u16*   xh        = Wt + NFEAT * NFEAT;

    // fixed-capacity packed buckets live in d_out (NB*BCAP ints = 8MB); dead before agg.
    int* packed = (int*)d_out;

    hipMemsetAsync(d_ws, 0, (size_t)(N + NBMAX) * sizeof(int), stream);

    int nchunk = (E + CHUNK - 1) / CHUNK;        // 782
    partition_kernel<<<nchunk, 256, 0, stream>>>(src, dst, E, cursor, packed, out_deg, NB);

    int nbc = (N + 127) >> 7;                    // 782 cast blocks
    fill_cast_kernel<<<NB + nbc + 1, 512, 0, stream>>>(packed, cursor,
                                                       row_start, inorm, csr_src,
                                                       x, out_deg, xh, W, Wt, N, E, NB, nbc);

    u16* aggh = (u16*)d_out;                     // strided: node i payload at byte i*512
    agg_bf16_kernel<<<(N + 7) / 8, 256, 0, stream>>>(xh, csr_src, row_start, inorm, aggh, N);

    mm_mfma_kernel<<<(N + 127) / 128, 256, 0, stream>>>(aggh, out, Wt, b, N);
}

// Round 15
// 220.399 us; speedup vs baseline: 1.1351x; 1.1351x over previous
//
#include <hip/hip_runtime.h>

#define NFEAT 128
#define BSHIFT 9
#define BNODES 512            // dst nodes per bucket
#define NBMAX 256             // max buckets (N <= 131072)
#define BCAP 9216             // fixed packed capacity per bucket (mean 8163 + 11 sigma)
#define CHUNK 4096            // edges per partition block (runs ~21 ints -> coalesced flush)

typedef __attribute__((ext_vector_type(8))) short bf16x8;
typedef __attribute__((ext_vector_type(4))) float f32x4;
typedef unsigned short u16;

__device__ inline u16 f2bf(float f) {            // RNE
    unsigned u = __float_as_uint(f);
    u += 0x7FFF + ((u >> 16) & 1);
    return (u16)(u >> 16);
}
__device__ inline float bf2f(u16 h) {
    return __uint_as_float((unsigned)h << 16);
}

// ---------------- partition v3 (r13-proven) + fused out-degree histogram ----------------
// packed[b*BCAP + slot] = ((dst & 511) << 17) | src ; cursor[b] counts edges in bucket b.
__global__ __launch_bounds__(512)
void partition_kernel(const int* __restrict__ src, const int* __restrict__ dst, int E,
                      int* __restrict__ cursor, int* __restrict__ packed,
                      int* __restrict__ out_deg, int NB) {
    __shared__ int cnt[NBMAX];            // hist -> local placement cursor
    __shared__ int loff[NBMAX];           // local exclusive offsets
    __shared__ int gbase[NBMAX];          // global run base per bucket
    __shared__ int sa[NBMAX], sb[NBMAX];
    __shared__ int sortv[CHUNK];          // 16 KiB sorted packed values
    __shared__ u16 sortb[CHUNK];          // 8 KiB bucket id per slot

    int tid = threadIdx.x;
    if (tid < NBMAX) cnt[tid] = 0;
    __syncthreads();

    int base = blockIdx.x * CHUNK;
    int endj = min(base + CHUNK, E);
    int ccnt = endj - base;

    for (int j = base + tid; j < endj; j += 512) {
        atomicAdd(&out_deg[src[j]], 1);            // fused deg histogram (fire-and-forget)
        atomicAdd(&cnt[dst[j] >> BSHIFT], 1);
    }
    __syncthreads();

    int v = (tid < NBMAX) ? cnt[tid] : 0;
    if (tid < NBMAX) sa[tid] = v;
    __syncthreads();
    int* s = sa; int* t = sb;
    for (int d = 1; d < NBMAX; d <<= 1) {
        if (tid < NBMAX) t[tid] = s[tid] + (tid >= d ? s[tid - d] : 0);
        __syncthreads();
        int* tmp = s; s = t; t = tmp;
    }
    if (tid < NBMAX) {
        int excl = s[tid] - v;
        loff[tid] = excl;
        cnt[tid] = excl;                               // local placement cursor
        gbase[tid] = v ? (tid * BCAP + atomicAdd(&cursor[tid], v)) : 0;
    }
    __syncthreads();

    for (int j = base + tid; j < endj; j += 512) {
        int d_ = dst[j];
        int bkt = d_ >> BSHIFT;
        int pos = atomicAdd(&cnt[bkt], 1);
        sortv[pos] = ((d_ & (BNODES - 1)) << 17) | src[j];
        sortb[pos] = (u16)bkt;
    }
    __syncthreads();

    // coalesced flush: consecutive p (same bucket run, ~21 ints) -> consecutive global addrs
    for (int p = tid; p < ccnt; p += 512) {
        int bkt = sortb[p];
        packed[gbase[bkt] + (p - loff[bkt])] = sortv[p];
    }
}

// ---- fat kernel: binfill sub-blocks (0..2NB-1) || cast (2NB..2NB+nbc-1) || Wt (last) -------
__global__ __launch_bounds__(512)
void fill_cast_kernel(const int* __restrict__ packed, const int* __restrict__ cursor,
                      int* __restrict__ row_start, float* __restrict__ inorm,
                      int* __restrict__ csr_src,
                      const float* __restrict__ x, const int* __restrict__ out_deg,
                      u16* __restrict__ xh, const float* __restrict__ W,
                      u16* __restrict__ Wt, int N, int E, int NB, int nbc) {
    int bid = blockIdx.x;
    int tid = threadIdx.x;

    if (bid < 2 * NB) {
        // ---- binfill sub-block: bucket bkt, half of its 512 nodes
        __shared__ int cnt[BNODES];
        __shared__ int sa[BNODES], sb[BNODES];
        __shared__ int ca[256], cb[256];
        int bkt = bid >> 1;
        int half = bid & 1;
        int beg = bkt * BCAP;
        int ccnt = cursor[bkt];

        // in-block csr_base: inclusive scan of cursor[0..NB) (196 ints, 256 scan threads)
        if (tid < 256) ca[tid] = (tid < NB) ? cursor[tid] : 0;
        __syncthreads();
        int* p = ca; int* q = cb;
        for (int d = 1; d < 256; d <<= 1) {
            if (tid < 256) q[tid] = p[tid] + (tid >= d ? p[tid - d] : 0);
            __syncthreads();
            int* tmp = p; p = q; q = tmp;
        }
        int csr0 = (bkt > 0) ? p[bkt - 1] : 0;
        if (bkt == 0 && half == 0 && tid == 0) row_start[N] = p[NB - 1];   // = E

        // full-bucket 512-node histogram (identical in both sub-blocks)
        cnt[tid] = 0;
        __syncthreads();
        for (int i = tid; i < ccnt; i += 512)
            atomicAdd(&cnt[packed[beg + i] >> 17], 1);
        __syncthreads();

        int v = cnt[tid];
        sa[tid] = v;
        __syncthreads();
        int* s = sa; int* t = sb;
        for (int d = 1; d < 512; d <<= 1) {
            t[tid] = s[tid] + (tid >= d ? s[tid - d] : 0);
            __syncthreads();
            int* tmp = s; s = t; t = tmp;
        }
        int excl = s[tid] - v;

        // write only this half's row_start/inorm (disjoint across sub-blocks)
        if ((tid >> 8) == half) {
            int n = (bkt << BSHIFT) + tid;
            if (n < N) {
                row_start[n] = csr0 + excl;
                inorm[n] = rsqrtf((float)max(v, 1));
            }
        }
        __syncthreads();

        cnt[tid] = csr0 + excl;          // reuse as global cursor
        __syncthreads();
        // scatter only this half's edges (disjoint csr_src regions)
        for (int i = tid; i < ccnt; i += 512) {
            int pk = packed[beg + i];
            int nd = pk >> 17;
            if ((nd >> 8) == half) {
                int slot = atomicAdd(&cnt[nd], 1);
                csr_src[slot] = pk & 0x1FFFF;
            }
        }
    } else if (bid < 2 * NB + nbc) {
        // ---- cast: xh[n][:] = bf16(x[n][:] * rsqrt(max(out_deg[n],1))), 128 rows/block
        int node0 = (bid - 2 * NB) << 7;
        for (int i = tid; i < 128 * 32; i += 512) {
            int r = i >> 5, f4 = i & 31;
            int n = node0 + r;
            if (n >= N) break;
            float sc = rsqrtf((float)max(out_deg[n], 1));
            float4 vv = *reinterpret_cast<const float4*>(&x[(size_t)n * NFEAT + f4 * 4]);
            ushort4 o;
            o.x = f2bf(vv.x * sc); o.y = f2bf(vv.y * sc);
            o.z = f2bf(vv.z * sc); o.w = f2bf(vv.w * sc);
            *reinterpret_cast<ushort4*>(&xh[(size_t)n * NFEAT + f4 * 4]) = o;
        }
    } else {
        // ---- Wt[col][k] = bf16(W[k][col])
        for (int i = tid; i < NFEAT * NFEAT; i += 512) {
            int col = i >> 7, k = i & 127;
            Wt[i] = f2bf(W[k * NFEAT + col]);
        }
    }
}

// ---------------- gather-aggregate (round-6 proven): half-wave per node, 8-wide ILP ----------
// Writes agg row (bf16, inorm-scaled) STRIDED at d_out + node*512B (payload first 256B).
__global__ __launch_bounds__(256)
void agg_bf16_kernel(const u16* __restrict__ xh, const int* __restrict__ csr_src,
                     const int* __restrict__ row_start, const float* __restrict__ inorm,
                     u16* __restrict__ aggh, int N) {
    int node = blockIdx.x * 8 + (threadIdx.x >> 5);
    if (node >= N) return;
    int lf = threadIdx.x & 31;
    int beg = row_start[node];
    int end = row_start[node + 1];
    const ushort4* xr = reinterpret_cast<const ushort4*>(xh);

    float4 acc = make_float4(0.f, 0.f, 0.f, 0.f);
    for (int i = beg; i < end; i += 8) {
        int s[8];
        float m[8];
        #pragma unroll
        for (int u = 0; u < 8; ++u) {          // phase 1: 8 independent index loads
            int j = i + u;
            bool ok = (j < end);
            s[u] = ok ? csr_src[j] : 0;
            m[u] = ok ? 1.f : 0.f;
        }
        ushort4 v[8];
        #pragma unroll
        for (int u = 0; u < 8; ++u)            // phase 2: 8 independent row gathers
            v[u] = xr[(size_t)s[u] * 32 + lf];
        #pragma unroll
        for (int u = 0; u < 8; ++u) {          // phase 3: masked accumulate
            acc.x = fmaf(m[u], bf2f(v[u].x), acc.x);
            acc.y = fmaf(m[u], bf2f(v[u].y), acc.y);
            acc.z = fmaf(m[u], bf2f(v[u].z), acc.z);
            acc.w = fmaf(m[u], bf2f(v[u].w), acc.w);
        }
    }
    float in_n = inorm[node];
    ushort4 o;
    o.x = f2bf(acc.x * in_n);
    o.y = f2bf(acc.y * in_n);
    o.z = f2bf(acc.z * in_n);
    o.w = f2bf(acc.w * in_n);
    *reinterpret_cast<ushort4*>(aggh + (size_t)node * 256 + lf * 4) = o;
}

// ---------------- MFMA projection: out = aggh @ W + b, in-place; Wt read direct (L1-hot) ----
__global__ __launch_bounds__(256)
void mm_mfma_kernel(const u16* __restrict__ aggh, float* outp,
                    const u16* __restrict__ Wt, const float* __restrict__ b, int N) {
    __shared__ u16 Al[NFEAT * NFEAT];   // 32 KiB (only A staged; Wt via L1/L2)
    int tid = threadIdx.x;
    int r0 = blockIdx.x * 128;

    for (int c = tid; c < 2048; c += 256) {
        int row = c >> 4, sub = c & 15;
        int grow = min(r0 + row, N - 1);
        int slot = sub ^ (row & 7);
        *reinterpret_cast<uint4*>(reinterpret_cast<char*>(Al) + row * 256 + slot * 16) =
            *reinterpret_cast<const uint4*>(reinterpret_cast<const char*>(aggh) +
                                            (size_t)grow * 512 + sub * 16);
    }
    __syncthreads();

    int lane = tid & 63;
    int wave = tid >> 6;
    int wr = wave >> 1, wc = wave & 1;
    int lrow = lane & 15, hi = lane >> 4;

    f32x4 zero = {0.f, 0.f, 0.f, 0.f};
    f32x4 acc[4][4];
    #pragma unroll
    for (int rt = 0; rt < 4; ++rt)
        #pragma unroll
        for (int ct = 0; ct < 4; ++ct) acc[rt][ct] = zero;

    #pragma unroll
    for (int ks = 0; ks < 4; ++ks) {
        int chunk = ks * 4 + hi;
        bf16x8 af[4], bfr[4];
        #pragma unroll
        for (int rt = 0; rt < 4; ++rt) {
            int row = wr * 64 + rt * 16 + lrow;
            af[rt] = *reinterpret_cast<bf16x8*>(reinterpret_cast<char*>(Al) + row * 256 +
                                                ((chunk ^ (row & 7)) * 16));
        }
        #pragma unroll
        for (int ct = 0; ct < 4; ++ct) {
            int col = wc * 64 + ct * 16 + lrow;
            bfr[ct] = *reinterpret_cast<const bf16x8*>(Wt + col * NFEAT + chunk * 8);
        }
        #pragma unroll
        for (int rt = 0; rt < 4; ++rt)
            #pragma unroll
            for (int ct = 0; ct < 4; ++ct)
                acc[rt][ct] = __builtin_amdgcn_mfma_f32_16x16x32_bf16(af[rt], bfr[ct],
                                                                     acc[rt][ct], 0, 0, 0);
    }

    #pragma unroll
    for (int ct = 0; ct < 4; ++ct) {
        int col = wc * 64 + ct * 16 + lrow;
        float bias = b[col];
        #pragma unroll
        for (int rt = 0; rt < 4; ++rt) {
            int rbase = r0 + wr * 64 + rt * 16 + hi * 4;
            #pragma unroll
            for (int q = 0; q < 4; ++q) {
                int row = rbase + q;
                if (row < N) outp[(size_t)row * NFEAT + col] = acc[rt][ct][q] + bias;
            }
        }
    }
}

extern "C" void kernel_launch(void* const* d_in, const int* in_sizes, int n_in,
                              void* d_out, int out_size, void* d_ws, size_t ws_size,
                              hipStream_t stream) {
    const float* x   = (const float*)d_in[0];
    const int*   src = (const int*)d_in[1];
    const int*   dst = (const int*)d_in[2];
    const float* W   = (const float*)d_in[3];
    const float* b   = (const float*)d_in[4];

    const int N = in_sizes[0] / NFEAT;   // 100000
    const int E = in_sizes[1];           // 1600000
    float* out = (float*)d_out;

    const int NB = (N + BNODES - 1) >> BSHIFT;   // 196

    // ws layout (ints unless noted):
    // [out_deg N][cursor NBMAX]  <- zeroed together
    // [row_start N+1][inorm N f32][csr_src E][align][Wt 16384 bf16][xh N*128 bf16]
    int*   out_deg   = (int*)d_ws;
    int*   cursor    = out_deg + N;
    int*   row_start = cursor + NBMAX;
    float* inorm     = (float*)(row_start + (N + 1));
    int*   csr_src   = (int*)(inorm + N);
    uintptr_t wt_addr = ((uintptr_t)(csr_src + E) + 31) & ~(uintptr_t)31;
    u16*   Wt        = (u16*)wt_addr;
    u16*   xh        = Wt + NFEAT * NFEAT;

    // fixed-capacity packed buckets live in d_out (NB*BCAP ints = 7.2MB); dead before agg.
    int* packed = (int*)d_out;

    hipMemsetAsync(d_ws, 0, (size_t)(N + NBMAX) * sizeof(int), stream);

    int nchunk = (E + CHUNK - 1) / CHUNK;        // 391
    partition_kernel<<<nchunk, 512, 0, stream>>>(src, dst, E, cursor, packed, out_deg, NB);

    int nbc = (N + 127) >> 7;                    // 782 cast blocks
    fill_cast_kernel<<<2 * NB + nbc + 1, 512, 0, stream>>>(packed, cursor,
                                                           row_start, inorm, csr_src,
                                                           x, out_deg, xh, W, Wt,
                                                           N, E, NB, nbc);

    u16* aggh = (u16*)d_out;                     // strided: node i payload at byte i*512
    agg_bf16_kernel<<<(N + 7) / 8, 256, 0, stream>>>(xh, csr_src, row_start, inorm, aggh, N);

    mm_mfma_kernel<<<(N + 127) / 128, 256, 0, stream>>>(aggh, out, Wt, b, N);
}

// Round 16
// 213.860 us; speedup vs baseline: 1.1698x; 1.0306x over previous
//
#include <hip/hip_runtime.h>

#define NFEAT 128
#define BSHIFT 9
#define BNODES 512            // dst nodes per bucket
#define NBMAX 256             // max buckets (N <= 131072; bucket id must fit u8 -> NB<=255)
#define BCAP 9216             // fixed packed capacity per bucket (mean 8192 + ~11 sigma)
#define CHUNK 4096            // edges per partition block (runs ~21 ints -> coalesced flush)

typedef __attribute__((ext_vector_type(8))) short bf16x8;
typedef __attribute__((ext_vector_type(4))) float f32x4;
typedef unsigned short u16;
typedef unsigned char u8;

__device__ inline u16 f2bf(float f) {            // RNE
    unsigned u = __float_as_uint(f);
    u += 0x7FFF + ((u >> 16) & 1);
    return (u16)(u >> 16);
}
__device__ inline float bf2f(u16 h) {
    return __uint_as_float((unsigned)h << 16);
}

// ---------------- partition v5: reg-cached edges + LDS counting sort + coalesced flush ------
// packed[b*BCAP + slot] = ((dst & 511) << 17) | src ; cursor[b] counts edges in bucket b.
__global__ __launch_bounds__(512)
void partition_kernel(const int* __restrict__ src, const int* __restrict__ dst, int E,
                      int* __restrict__ cursor, int* __restrict__ packed,
                      int* __restrict__ out_deg, int NB) {
    __shared__ int cnt[NBMAX];            // hist -> local placement cursor
    __shared__ int gml[NBMAX];            // gbase[b] - loff[b]
    __shared__ int sa[NBMAX], sb[NBMAX];
    __shared__ int sortv[CHUNK];          // 16 KiB sorted packed values
    __shared__ u8  sortb[CHUNK];          // 4 KiB bucket id per slot

    int tid = threadIdx.x;
    if (tid < NBMAX) cnt[tid] = 0;
    __syncthreads();

    int base = blockIdx.x * CHUNK;
    int endj = min(base + CHUNK, E);
    int ccnt = endj - base;

    // phase 0: register-cache this thread's 8 edges (single global read of src/dst)
    int rs[8], rd[8];
    #pragma unroll
    for (int u = 0; u < 8; ++u) {
        int j = base + tid + u * 512;
        if (j < endj) { rd[u] = dst[j]; rs[u] = src[j]; }
    }
    // phase 1: histograms (LDS bucket counts + fused global out-deg, fire-and-forget)
    #pragma unroll
    for (int u = 0; u < 8; ++u) {
        int j = base + tid + u * 512;
        if (j < endj) {
            atomicAdd(&out_deg[rs[u]], 1);
            atomicAdd(&cnt[rd[u] >> BSHIFT], 1);
        }
    }
    __syncthreads();

    // phase 2: scan 256 bins; reserve global runs; precompute gbase-loff
    int v = (tid < NBMAX) ? cnt[tid] : 0;
    if (tid < NBMAX) sa[tid] = v;
    __syncthreads();
    int* s = sa; int* t = sb;
    for (int d = 1; d < NBMAX; d <<= 1) {
        if (tid < NBMAX) t[tid] = s[tid] + (tid >= d ? s[tid - d] : 0);
        __syncthreads();
        int* tmp = s; s = t; t = tmp;
    }
    if (tid < NBMAX) {
        int excl = s[tid] - v;
        cnt[tid] = excl;                               // local placement cursor
        int gb = v ? (tid * BCAP + atomicAdd(&cursor[tid], v)) : 0;
        gml[tid] = gb - excl;
    }
    __syncthreads();

    // phase 3: place into LDS sorted order (from registers)
    #pragma unroll
    for (int u = 0; u < 8; ++u) {
        int j = base + tid + u * 512;
        if (j < endj) {
            int bkt = rd[u] >> BSHIFT;
            int pos = atomicAdd(&cnt[bkt], 1);
            sortv[pos] = ((rd[u] & (BNODES - 1)) << 17) | rs[u];
            sortb[pos] = (u8)bkt;
        }
    }
    __syncthreads();

    // phase 4: coalesced flush (runs ~21 ints); addr = gml[bkt] + p
    for (int p = tid; p < ccnt; p += 512) {
        int bkt = sortb[p];
        packed[gml[bkt] + p] = sortv[p];
    }
}

// ---- fat kernel: binfill (blocks 0..NB-1, r13 single-block form + reg-cache) ||
// ---- cast (NB..NB+nbc-1) || Wt (last) ------------------------------------------------------
__global__ __launch_bounds__(512)
void fill_cast_kernel(const int* __restrict__ packed, const int* __restrict__ cursor,
                      int* __restrict__ row_start, float* __restrict__ inorm,
                      int* __restrict__ csr_src,
                      const float* __restrict__ x, const int* __restrict__ out_deg,
                      u16* __restrict__ xh, const float* __restrict__ W,
                      u16* __restrict__ Wt, int N, int E, int NB, int nbc) {
    int bid = blockIdx.x;
    int tid = threadIdx.x;

    if (bid < NB) {
        // ---- binfill: per-bucket node-sort of packed -> compact csr_src + row_start + inorm
        __shared__ int cnt[BNODES];
        __shared__ int sa[BNODES], sb[BNODES];
        __shared__ int ca[256], cb[256];
        int bkt = bid;
        int node0 = bkt << BSHIFT;
        int nn = min(BNODES, N - node0);
        int beg = bkt * BCAP;
        int ccnt = cursor[bkt];

        // in-block csr_base: inclusive scan of cursor[0..NB) (196 ints, 256 scan threads)
        if (tid < 256) ca[tid] = (tid < NB) ? cursor[tid] : 0;
        __syncthreads();
        int* p = ca; int* q = cb;
        for (int d = 1; d < 256; d <<= 1) {
            if (tid < 256) q[tid] = p[tid] + (tid >= d ? p[tid - d] : 0);
            __syncthreads();
            int* tmp = p; p = q; q = tmp;
        }
        int csr0 = (bkt > 0) ? p[bkt - 1] : 0;
        if (bkt == 0 && tid == 0) row_start[N] = E;

        // register-cache this block's packed edges (up to 8192; tail via global loop)
        int rp[16];
        int nv = min(ccnt, 8192);
        cnt[tid] = 0;
        __syncthreads();
        #pragma unroll
        for (int u = 0; u < 16; ++u) {
            int i = tid + u * 512;
            if (i < nv) rp[u] = packed[beg + i];
        }
        #pragma unroll
        for (int u = 0; u < 16; ++u) {
            int i = tid + u * 512;
            if (i < nv) atomicAdd(&cnt[rp[u] >> 17], 1);
        }
        for (int i = 8192 + tid; i < ccnt; i += 512)
            atomicAdd(&cnt[packed[beg + i] >> 17], 1);
        __syncthreads();

        int v = cnt[tid];
        sa[tid] = v;
        __syncthreads();
        int* s = sa; int* t = sb;
        for (int d = 1; d < 512; d <<= 1) {
            t[tid] = s[tid] + (tid >= d ? s[tid - d] : 0);
            __syncthreads();
            int* tmp = s; s = t; t = tmp;
        }
        int excl = s[tid] - v;

        if (tid < nn) {
            row_start[node0 + tid] = csr0 + excl;
            inorm[node0 + tid] = rsqrtf((float)max(v, 1));
        }
        __syncthreads();

        cnt[tid] = csr0 + excl;          // reuse as global cursor
        __syncthreads();
        #pragma unroll
        for (int u = 0; u < 16; ++u) {
            int i = tid + u * 512;
            if (i < nv) {
                int slot = atomicAdd(&cnt[rp[u] >> 17], 1);
                csr_src[slot] = rp[u] & 0x1FFFF;
            }
        }
        for (int i = 8192 + tid; i < ccnt; i += 512) {
            int pk = packed[beg + i];
            int slot = atomicAdd(&cnt[pk >> 17], 1);
            csr_src[slot] = pk & 0x1FFFF;
        }
    } else if (bid < NB + nbc) {
        // ---- cast: xh[n][:] = bf16(x[n][:] * rsqrt(max(out_deg[n],1))), 128 rows/block
        int node0 = (bid - NB) << 7;
        for (int i = tid; i < 128 * 32; i += 512) {
            int r = i >> 5, f4 = i & 31;
            int n = node0 + r;
            if (n >= N) break;
            float sc = rsqrtf((float)max(out_deg[n], 1));
            float4 vv = *reinterpret_cast<const float4*>(&x[(size_t)n * NFEAT + f4 * 4]);
            ushort4 o;
            o.x = f2bf(vv.x * sc); o.y = f2bf(vv.y * sc);
            o.z = f2bf(vv.z * sc); o.w = f2bf(vv.w * sc);
            *reinterpret_cast<ushort4*>(&xh[(size_t)n * NFEAT + f4 * 4]) = o;
        }
    } else {
        // ---- Wt[col][k] = bf16(W[k][col])
        for (int i = tid; i < NFEAT * NFEAT; i += 512) {
            int col = i >> 7, k = i & 127;
            Wt[i] = f2bf(W[k * NFEAT + col]);
        }
    }
}

// ---------------- gather-aggregate (round-6 proven): half-wave per node, 8-wide ILP ----------
// Writes agg row (bf16, inorm-scaled) STRIDED at d_out + node*512B (payload first 256B).
__global__ __launch_bounds__(256)
void agg_bf16_kernel(const u16* __restrict__ xh, const int* __restrict__ csr_src,
                     const int* __restrict__ row_start, const float* __restrict__ inorm,
                     u16* __restrict__ aggh, int N) {
    int node = blockIdx.x * 8 + (threadIdx.x >> 5);
    if (node >= N) return;
    int lf = threadIdx.x & 31;
    int beg = row_start[node];
    int end = row_start[node + 1];
    const ushort4* xr = reinterpret_cast<const ushort4*>(xh);

    float4 acc = make_float4(0.f, 0.f, 0.f, 0.f);
    for (int i = beg; i < end; i += 8) {
        int s[8];
        float m[8];
        #pragma unroll
        for (int u = 0; u < 8; ++u) {          // phase 1: 8 independent index loads
            int j = i + u;
            bool ok = (j < end);
            s[u] = ok ? csr_src[j] : 0;
            m[u] = ok ? 1.f : 0.f;
        }
        ushort4 v[8];
        #pragma unroll
        for (int u = 0; u < 8; ++u)            // phase 2: 8 independent row gathers
            v[u] = xr[(size_t)s[u] * 32 + lf];
        #pragma unroll
        for (int u = 0; u < 8; ++u) {          // phase 3: masked accumulate
            acc.x = fmaf(m[u], bf2f(v[u].x), acc.x);
            acc.y = fmaf(m[u], bf2f(v[u].y), acc.y);
            acc.z = fmaf(m[u], bf2f(v[u].z), acc.z);
            acc.w = fmaf(m[u], bf2f(v[u].w), acc.w);
        }
    }
    float in_n = inorm[node];
    ushort4 o;
    o.x = f2bf(acc.x * in_n);
    o.y = f2bf(acc.y * in_n);
    o.z = f2bf(acc.z * in_n);
    o.w = f2bf(acc.w * in_n);
    *reinterpret_cast<ushort4*>(aggh + (size_t)node * 256 + lf * 4) = o;
}

// ---------------- MFMA projection: out = aggh @ W + b, in-place; Wt read direct (L1-hot) ----
__global__ __launch_bounds__(256)
void mm_mfma_kernel(const u16* __restrict__ aggh, float* outp,
                    const u16* __restrict__ Wt, const float* __restrict__ b, int N) {
    __shared__ u16 Al[NFEAT * NFEAT];   // 32 KiB (only A staged; Wt via L1/L2)
    int tid = threadIdx.x;
    int r0 = blockIdx.x * 128;

    for (int c = tid; c < 2048; c += 256) {
        int row = c >> 4, sub = c & 15;
        int grow = min(r0 + row, N - 1);
        int slot = sub ^ (row & 7);
        *reinterpret_cast<uint4*>(reinterpret_cast<char*>(Al) + row * 256 + slot * 16) =
            *reinterpret_cast<const uint4*>(reinterpret_cast<const char*>(aggh) +
                                            (size_t)grow * 512 + sub * 16);
    }
    __syncthreads();

    int lane = tid & 63;
    int wave = tid >> 6;
    int wr = wave >> 1, wc = wave & 1;
    int lrow = lane & 15, hi = lane >> 4;

    f32x4 zero = {0.f, 0.f, 0.f, 0.f};
    f32x4 acc[4][4];
    #pragma unroll
    for (int rt = 0; rt < 4; ++rt)
        #pragma unroll
        for (int ct = 0; ct < 4; ++ct) acc[rt][ct] = zero;

    #pragma unroll
    for (int ks = 0; ks < 4; ++ks) {
        int chunk = ks * 4 + hi;
        bf16x8 af[4], bfr[4];
        #pragma unroll
        for (int rt = 0; rt < 4; ++rt) {
            int row = wr * 64 + rt * 16 + lrow;
            af[rt] = *reinterpret_cast<bf16x8*>(reinterpret_cast<char*>(Al) + row * 256 +
                                                ((chunk ^ (row & 7)) * 16));
        }
        #pragma unroll
        for (int ct = 0; ct < 4; ++ct) {
            int col = wc * 64 + ct * 16 + lrow;
            bfr[ct] = *reinterpret_cast<const bf16x8*>(Wt + col * NFEAT + chunk * 8);
        }
        #pragma unroll
        for (int rt = 0; rt < 4; ++rt)
            #pragma unroll
            for (int ct = 0; ct < 4; ++ct)
                acc[rt][ct] = __builtin_amdgcn_mfma_f32_16x16x32_bf16(af[rt], bfr[ct],
                                                                     acc[rt][ct], 0, 0, 0);
    }

    #pragma unroll
    for (int ct = 0; ct < 4; ++ct) {
        int col = wc * 64 + ct * 16 + lrow;
        float bias = b[col];
        #pragma unroll
        for (int rt = 0; rt < 4; ++rt) {
            int rbase = r0 + wr * 64 + rt * 16 + hi * 4;
            #pragma unroll
            for (int q = 0; q < 4; ++q) {
                int row = rbase + q;
                if (row < N) outp[(size_t)row * NFEAT + col] = acc[rt][ct][q] + bias;
            }
        }
    }
}

extern "C" void kernel_launch(void* const* d_in, const int* in_sizes, int n_in,
                              void* d_out, int out_size, void* d_ws, size_t ws_size,
                              hipStream_t stream) {
    const float* x   = (const float*)d_in[0];
    const int*   src = (const int*)d_in[1];
    const int*   dst = (const int*)d_in[2];
    const float* W   = (const float*)d_in[3];
    const float* b   = (const float*)d_in[4];

    const int N = in_sizes[0] / NFEAT;   // 100000
    const int E = in_sizes[1];           // 1600000
    float* out = (float*)d_out;

    const int NB = (N + BNODES - 1) >> BSHIFT;   // 196

    // ws layout (ints unless noted):
    // [out_deg N][cursor NBMAX]  <- zeroed together
    // [row_start N+1][inorm N f32][csr_src E][align][Wt 16384 bf16][xh N*128 bf16]
    int*   out_deg   = (int*)d_ws;
    int*   cursor    = out_deg + N;
    int*   row_start = cursor + NBMAX;
    float* inorm     = (float*)(row_start + (N + 1));
    int*   csr_src   = (int*)(inorm + N);
    uintptr_t wt_addr = ((uintptr_t)(csr_src + E) + 31) & ~(uintptr_t)31;
    u16*   Wt        = (u16*)wt_addr;
    u16*   xh        = Wt + NFEAT * NFEAT;

    // fixed-capacity packed buckets live in d_out (NB*BCAP ints = 7.2MB); dead before agg.
    int* packed = (int*)d_out;

    hipMemsetAsync(d_ws, 0, (size_t)(N + NBMAX) * sizeof(int), stream);

    int nchunk = (E + CHUNK - 1) / CHUNK;        // 391
    partition_kernel<<<nchunk, 512, 0, stream>>>(src, dst, E, cursor, packed, out_deg, NB);

    int nbc = (N + 127) >> 7;                    // 782 cast blocks
    fill_cast_kernel<<<NB + nbc + 1, 512, 0, stream>>>(packed, cursor,
                                                       row_start, inorm, csr_src,
                                                       x, out_deg, xh, W, Wt,
                                                       N, E, NB, nbc);

    u16* aggh = (u16*)d_out;                     // strided: node i payload at byte i*512
    agg_bf16_kernel<<<(N + 7) / 8, 256, 0, stream>>>(xh, csr_src, row_start, inorm, aggh, N);

    mm_mfma_kernel<<<(N + 127) / 128, 256, 0, stream>>>(aggh, out, Wt, b, N);
}